// Round 9
// baseline (99306.946 us; speedup 1.0000x reference)
//
#include <hip/hip_runtime.h>
#include <math.h>

// B=256 T=512 DIN=25 P=128 HID=256 3H=768 L=5 Q=0.15 EPS=1e-5
// Full-fp32. Single batch group when ws allows (Bg=256; ws>=659MB known from
// R2), chunked time axis (CH=64 or 32). Fused rounds: recur blocks FIRST
// (4 samples per 256-thr block — one 768KB Whh stream serves 4 samples, L2
// demand /4 vs R8; ~5.5us/step per-CU port floor), 128x128 8x8 GEMM blocks
// fill the remaining CUs. Recur critical path = 2560 steps x ~5.5us ~= 14ms.

// ---------------- stable sort + per-group chunk count ----------------
__global__ __launch_bounds__(256)
void sort_k(const int* __restrict__ len, int* __restrict__ perm,
            int* __restrict__ nchp, int Bg, int CHv)
{
    __shared__ int ll[256];
    __shared__ int lp[256];
    const int i = threadIdx.x;
    const int li = len[i];
    ll[i] = li;
    __syncthreads();
    int rk = 0;
    for (int j = 0; j < 256; j++) {
        int lj = ll[j];
        rk += (lj < li || (lj == li && j < i)) ? 1 : 0;
    }
    lp[rk] = i;
    __syncthreads();
    perm[i] = lp[i];
    const int ngrp = 256 / Bg;
    const int rmax = 512 / CHv;
    if (i < ngrp) {
        int mx = ll[lp[i * Bg + Bg - 1]];      // ascending -> last rank is max
        int nch = (mx + CHv - 1) / CHv;
        nchp[i] = nch < 1 ? 1 : (nch > rmax ? rmax : nch);
    }
}

// ---------------- Whh transpose: whhT[l][d][k][c] ----------------
__global__ __launch_bounds__(256)
void prep_whhT_k(const float* __restrict__ Whh0, const float* __restrict__ Whh,
                 float* __restrict__ out)
{
    int id = blockIdx.x * 256 + threadIdx.x;   // exactly 1,966,080 threads
    int u = id / 196608, rr = id % 196608;     // u = l*2+d
    int k = rr / 768, c = rr % 768;
    int l = u >> 1, d = u & 1;
    out[id] = (l == 0) ? Whh0[(size_t)(d * 768 + c) * 256 + k]
                       : Whh[(size_t)(((l - 1) * 2 + d) * 768 + c) * 256 + k];
}

// ---------------- input projection: LN -> FC(25->128) -> GELU -> FC(128->128) --
__global__ __launch_bounds__(128)
void input_proj_k(const float* __restrict__ x, const int* __restrict__ lengths,
                  const int* __restrict__ perm,
                  const float* __restrict__ lng, const float* __restrict__ lnb,
                  const float* __restrict__ w1, const float* __restrict__ b1v,
                  const float* __restrict__ w2, const float* __restrict__ b2v,
                  float* __restrict__ out, int g0)
{
    const int btl = blockIdx.x;
    const int sl  = btl >> 9;
    const int t   = btl & 511;
    const int b   = perm[g0 + sl];
    if (t >= lengths[b]) return;               // masked rows never read downstream
    const int tid = threadIdx.x;
    __shared__ float xs[25];
    __shared__ float xn[25];
    __shared__ float hs[128];
    if (tid < 25) xs[tid] = x[((size_t)b * 512 + t) * 25 + tid];
    __syncthreads();
    if (tid < 25) {
        float mu = 0.f;
        #pragma unroll
        for (int k = 0; k < 25; k++) mu += xs[k];
        mu *= (1.f / 25.f);
        float var = 0.f;
        #pragma unroll
        for (int k = 0; k < 25; k++) { float dd = xs[k] - mu; var += dd * dd; }
        var *= (1.f / 25.f);
        float rstd = 1.f / sqrtf(var + 1e-5f);
        xn[tid] = (xs[tid] - mu) * rstd * lng[tid] + lnb[tid];
    }
    __syncthreads();
    float a = b1v[tid];
    #pragma unroll
    for (int k = 0; k < 25; k++) a = fmaf(xn[k], w1[k * 128 + tid], a);
    float ge = 0.5f * a * (1.f + erff(a * 0.70710678118654752440f));
    hs[tid] = ge;
    __syncthreads();
    float o = b2v[tid];
    #pragma unroll 8
    for (int k = 0; k < 128; k++) o = fmaf(hs[k], w2[k * 128 + tid], o);
    out[(size_t)btl * 128 + tid] = o;
}

// ---------------- fused round: recur(chunk r-1) first, gemm(chunk r) ----------
// recur: NR = Bg/2 blocks, 4 samples + 1 dir each, 256 thr; thread j owns
//   hidden unit j (gate cols j,256+j,512+j) for 4 samples; h double-buffered
//   in LDS; ONE Whh stream per block-step serves 4 samples.
// gemm: 128x128 tile, 8x8 per thread; rows = spt samples x CHv positions.
__global__ __launch_bounds__(256)
void round_k(const float* __restrict__ A, int K,
             const float* __restrict__ W,      // raw Wih layer slice [2][768][K]
             const float* __restrict__ bi,     // [2][768]
             const int* __restrict__ lengths, const int* __restrict__ perm,
             const int* __restrict__ nchp, int gidx, int g0, int Bg,
             int CHv, int chsh,
             float* __restrict__ xw_w,         // gemm out (round r)
             const float* __restrict__ xw_r,   // recur in (round r-1)
             const float* __restrict__ whhT,   // layer slice [2][256][768]
             const float* __restrict__ bhh,    // [2][768]
             float* __restrict__ Y,            // bout [Bg*512][512]
             float* __restrict__ hstate,       // [2*Bg][256]
             int NR, int r)
{
    __shared__ float As[8][132];       // gemm A stage [k][m]
    __shared__ float Bs[8][132];       // gemm B stage [k][n]
    __shared__ float h_s[2][256][4];   // recur double-buffered h [k][sample]

    const int tid = threadIdx.x;
    const int nch = nchp[gidx];

    if ((int)blockIdx.x < NR) {
        // ================= recur role =================
        const int half = NR >> 1;
        const int d    = ((int)blockIdx.x >= half) ? 1 : 0;
        const int tile = (int)blockIdx.x - d * half;
        const int b0   = tile * 4;
        const int lo   = d ? (nch - r) * CHv : (r - 1) * CHv;
        if (lo < 0 || lo >= 512) return;
        const int first = (r == 1);

        int nst[4];
        int nmax = 0;
        #pragma unroll
        for (int s = 0; s < 4; s++) {
            int L = lengths[perm[g0 + b0 + s]];
            int n = min(lo + CHv, L) - lo;
            nst[s] = (n < 0) ? 0 : n;
            nmax = max(nmax, nst[s]);
        }
        if (!first && nmax <= 0) return;       // hstate already valid

        const int j = tid;                     // hidden unit
        float* hg = hstate + (size_t)(d * Bg + b0) * 256;
        #pragma unroll
        for (int s = 0; s < 4; s++)
            h_s[0][j][s] = first ? 0.f : hg[s * 256 + j];
        __syncthreads();

        const float* Wd  = whhT + (size_t)d * 196608;   // [256][768]
        const float* xwd = xw_r + (size_t)(d * Bg + b0) * ((size_t)CHv * 768);
        const float bh0 = bhh[d * 768 + j];
        const float bh1 = bhh[d * 768 + 256 + j];
        const float bh2 = bhh[d * 768 + 512 + j];

        int par = 0;
        for (int st = 0; st < nmax; st++) {
            float ar[4] = {}, az[4] = {}, an[4] = {};
            const float* wp = Wd + j;
            #pragma unroll 4
            for (int k = 0; k < 256; k++) {
                float wr = wp[0];              // col j     (coalesced 256B)
                float wz = wp[256];            // col 256+j
                float wn = wp[512];            // col 512+j
                wp += 768;
                float4 h4 = *(const float4*)&h_s[par][k][0];   // LDS broadcast
                ar[0] = fmaf(h4.x, wr, ar[0]); ar[1] = fmaf(h4.y, wr, ar[1]);
                ar[2] = fmaf(h4.z, wr, ar[2]); ar[3] = fmaf(h4.w, wr, ar[3]);
                az[0] = fmaf(h4.x, wz, az[0]); az[1] = fmaf(h4.y, wz, az[1]);
                az[2] = fmaf(h4.z, wz, az[2]); az[3] = fmaf(h4.w, wz, az[3]);
                an[0] = fmaf(h4.x, wn, an[0]); an[1] = fmaf(h4.y, wn, an[1]);
                an[2] = fmaf(h4.z, wn, an[2]); an[3] = fmaf(h4.w, wn, an[3]);
            }
            float4 hv4 = *(const float4*)&h_s[par][j][0];
            float hold[4] = {hv4.x, hv4.y, hv4.z, hv4.w};
            float hnew[4];
            #pragma unroll
            for (int s = 0; s < 4; s++) {
                float hn = hold[s];
                if (st < nst[s]) {             // near-uniform after sort
                    int p = d ? (lo + nst[s] - 1 - st) : (lo + st);
                    const float* xr = xwd + ((size_t)s * CHv + (p - lo)) * 768;
                    float rg = 1.f / (1.f + expf(-(xr[j] + ar[s] + bh0)));
                    float zg = 1.f / (1.f + expf(-(xr[256 + j] + az[s] + bh1)));
                    float ng = tanhf(xr[512 + j] + rg * (an[s] + bh2));
                    hn = (1.f - zg) * ng + zg * hold[s];
                    Y[((size_t)((b0 + s) * 512 + p)) * 512 + d * 256 + j] = hn;
                }
                hnew[s] = hn;
            }
            *(float4*)&h_s[par ^ 1][j][0] =
                make_float4(hnew[0], hnew[1], hnew[2], hnew[3]);
            par ^= 1;
            __syncthreads();
        }
        #pragma unroll
        for (int s = 0; s < 4; s++) hg[s * 256 + j] = h_s[par][j][s];
    } else {
        // ================= gemm role (128x128, 8x8/thread) =================
        const int gid  = blockIdx.x - NR;
        const int nt   = gid % 6;
        const int rest = gid / 6;
        const int nRT  = (Bg << 1) * CHv >> 7;         // row tiles, both dirs
        const int hRT  = nRT >> 1;
        const int dirg = (rest >= hRT) ? 1 : 0;
        const int rt   = rest - dirg * hRT;
        const int spt  = 128 >> chsh;                  // samples per row tile
        const int s0   = rt * spt;
        const int lo   = dirg ? (nch - 1 - r) * CHv : r * CHv;
        if (lo < 0 || lo >= 512) return;
        if (lengths[perm[g0 + s0 + spt - 1]] <= lo) return;  // ascending sort

        float acc[8][8] = {};
        const int tx8 = (tid & 15) << 3;
        const int ty8 = (tid >> 4) << 3;
        const int am  = tid >> 1;                      // A stage row 0..127
        const int ah  = (tid & 1) << 2;                // k offset 0/4
        const int cb  = dirg * 768 + nt * 128;

        const int sA = s0 + (am >> chsh);
        const int pA = lo + (am & (CHv - 1));
        const float* Ap = A + ((size_t)sA * 512 + pA) * K + ah;
        const float* Wp = W + ((size_t)cb + am) * K + ah;   // B col am

        for (int k0 = 0; k0 < K; k0 += 8) {
            float4 av = *(const float4*)(Ap + k0);
            float4 bv = *(const float4*)(Wp + k0);
            __syncthreads();
            As[ah + 0][am] = av.x; As[ah + 1][am] = av.y;
            As[ah + 2][am] = av.z; As[ah + 3][am] = av.w;
            Bs[ah + 0][am] = bv.x; Bs[ah + 1][am] = bv.y;
            Bs[ah + 2][am] = bv.z; Bs[ah + 3][am] = bv.w;
            __syncthreads();
            #pragma unroll
            for (int kk = 0; kk < 8; kk++) {
                float4 a0 = *(const float4*)&As[kk][ty8];
                float4 a1 = *(const float4*)&As[kk][ty8 + 4];
                float4 b0 = *(const float4*)&Bs[kk][tx8];
                float4 b1 = *(const float4*)&Bs[kk][tx8 + 4];
                float ax[8] = {a0.x, a0.y, a0.z, a0.w, a1.x, a1.y, a1.z, a1.w};
                float bx[8] = {b0.x, b0.y, b0.z, b0.w, b1.x, b1.y, b1.z, b1.w};
                #pragma unroll
                for (int i = 0; i < 8; i++)
                    #pragma unroll
                    for (int jj = 0; jj < 8; jj++)
                        acc[i][jj] = fmaf(ax[i], bx[jj], acc[i][jj]);
            }
        }
        float bsv[8];
        #pragma unroll
        for (int jj = 0; jj < 8; jj++) bsv[jj] = bi[cb + tx8 + jj];
        #pragma unroll
        for (int i = 0; i < 8; i++) {
            const int row = ty8 + i;
            const int sl  = s0 + (row >> chsh);
            const int po  = row & (CHv - 1);
            float* o = xw_w + (size_t)((dirg * Bg + sl) * CHv + po) * 768
                     + nt * 128 + tx8;
            float4 c0 = make_float4(acc[i][0] + bsv[0], acc[i][1] + bsv[1],
                                    acc[i][2] + bsv[2], acc[i][3] + bsv[3]);
            float4 c1 = make_float4(acc[i][4] + bsv[4], acc[i][5] + bsv[5],
                                    acc[i][6] + bsv[6], acc[i][7] + bsv[7]);
            *(float4*)(o)     = c0;
            *(float4*)(o + 4) = c1;
        }
    }
}

// ---------------- top-Q pooling + classifier head ----------------
__global__ __launch_bounds__(256)
void pool_k(const float* __restrict__ H, const int* __restrict__ lengths,
            const int* __restrict__ perm,
            const float* __restrict__ Wc, const float* __restrict__ bcp,
            float* __restrict__ out, int g0)
{
    const int bl = blockIdx.x;
    const int b  = perm[g0 + bl];
    const int tid = threadIdx.x;
    __shared__ float sc[512];
    __shared__ int   sel[128];
    __shared__ int   nsel;
    __shared__ float red[256];
    const int len = lengths[b];
    const int k = max(1, (int)ceilf((float)len * 0.15f));   // jnp fp32 semantics
    if (tid == 0) nsel = 0;
    for (int t = tid; t < 512; t += 256) {
        float s;
        if (t < len) {
            const float* row = H + ((size_t)bl * 512 + t) * 512;
            float acc = 0.f;
            for (int j = 0; j < 512; j++) acc = fmaf(row[j], row[j], acc);
            s = sqrtf(acc);
        } else s = -1e9f;
        sc[t] = s;
    }
    __syncthreads();
    // stable top-k: include t iff (#strictly greater) + (#equal, smaller idx) < k
    for (int t = tid; t < 512; t += 256) {
        if (t < len) {
            const float s = sc[t];
            int cnt = 0;
            for (int u = 0; u < 512; u++) {
                float su = sc[u];
                cnt += (su > s || (su == s && u < t)) ? 1 : 0;
            }
            if (cnt < k) { int p = atomicAdd(&nsel, 1); sel[p] = t; }
        }
    }
    __syncthreads();
    const int ns = nsel;                       // == k
    float part = 0.f;
    for (int j = tid; j < 512; j += 256) {
        float acc = 0.f;
        for (int i = 0; i < ns; i++)
            acc += H[((size_t)bl * 512 + sel[i]) * 512 + j];
        part += (acc / (float)k) * Wc[j];
    }
    red[tid] = part;
    __syncthreads();
    for (int s2 = 128; s2 > 0; s2 >>= 1) {
        if (tid < s2) red[tid] += red[tid + s2];
        __syncthreads();
    }
    if (tid == 0) out[b] = red[0] + bcp[0];
}

// ---------------- host ----------------
static inline size_t alup(size_t x) { return (x + 255) & ~255ull; }

static size_t tier_bytes(int Bg, int CHv)
{
    return 2 * alup((size_t)Bg * 512 * 512 * 4)            // H ping-pong
         + 2 * alup((size_t)Bg * 2 * CHv * 768 * 4)        // xw ping-pong
         + alup(1966080ull * 4)                            // whhT
         + alup((size_t)Bg * 2 * 256 * 4)                  // hstate
         + alup(2048);                                     // perm + nch
}

extern "C" void kernel_launch(void* const* d_in, const int* in_sizes, int n_in,
                              void* d_out, int out_size, void* d_ws, size_t ws_size,
                              hipStream_t stream)
{
    const float* x    = (const float*)d_in[0];
    const int*   len  = (const int*)  d_in[1];
    const float* ln_g = (const float*)d_in[2];
    const float* ln_b = (const float*)d_in[3];
    const float* w1   = (const float*)d_in[4];
    const float* b1   = (const float*)d_in[5];
    const float* w2   = (const float*)d_in[6];
    const float* b2   = (const float*)d_in[7];
    const float* Wih0 = (const float*)d_in[8];
    const float* Whh0 = (const float*)d_in[9];
    const float* bih0 = (const float*)d_in[10];
    const float* bhh0 = (const float*)d_in[11];
    const float* Wih  = (const float*)d_in[12];
    const float* Whh  = (const float*)d_in[13];
    const float* bih  = (const float*)d_in[14];
    const float* bhh  = (const float*)d_in[15];
    const float* Wc   = (const float*)d_in[16];
    const float* bc   = (const float*)d_in[17];
    float* out = (float*)d_out;

    // tier ladder: prefer one big group; CH=32 variant guaranteed <= 646MB
    const int tBg[7] = {256, 256, 128, 128, 64, 32, 16};
    const int tCH[7] = { 64,  32,  64,  32, 64, 64, 64};
    int Bg = 0, CHv = 64;
    for (int i = 0; i < 7; i++)
        if (ws_size >= tier_bytes(tBg[i], tCH[i])) { Bg = tBg[i]; CHv = tCH[i]; break; }
    if (Bg == 0) return;
    const int chsh = (CHv == 64) ? 6 : 5;
    const int RMAX = 512 / CHv;

    char* ws = (char*)d_ws;
    size_t off = 0;
    auto alloc = [&](size_t bytes) { size_t o = off; off += alup(bytes); return o; };
    float* h0   = (float*)(ws + alloc((size_t)Bg * 512 * 512 * 4));
    float* h1   = (float*)(ws + alloc((size_t)Bg * 512 * 512 * 4));
    float* xwA  = (float*)(ws + alloc((size_t)Bg * 2 * CHv * 768 * 4));
    float* xwB  = (float*)(ws + alloc((size_t)Bg * 2 * CHv * 768 * 4));
    float* whhT = (float*)(ws + alloc(1966080ull * 4));
    float* hst  = (float*)(ws + alloc((size_t)Bg * 2 * 256 * 4));
    int*   perm = (int*)  (ws + alloc(2048));
    int*   nchp = perm + 256;
    float* xwbuf[2] = {xwA, xwB};

    sort_k<<<1, 256, 0, stream>>>(len, perm, nchp, Bg, CHv);
    prep_whhT_k<<<7680, 256, 0, stream>>>(Whh0, Whh, whhT);

    const int NRfull = Bg / 2;                 // recur blocks (2 dirs x Bg/4)
    const int NGfull = 6 * ((Bg * 2 * CHv) >> 7);

    for (int g0 = 0; g0 < 256; g0 += Bg) {
        const int gidx = g0 / Bg;
        input_proj_k<<<Bg * 512, 128, 0, stream>>>(x, len, perm, ln_g, ln_b,
                                                   w1, b1, w2, b2, h0, g0);
        float* bin = h0;
        float* bout = h1;
        for (int l = 0; l < 5; l++) {
            const int K = (l == 0) ? 128 : 512;
            const float* Wl  = (l == 0) ? Wih0 : (Wih + (size_t)(l - 1) * 2 * 768 * 512);
            const float* bil = (l == 0) ? bih0 : (bih + (size_t)(l - 1) * 1536);
            const float* whl = whhT + (size_t)l * 393216;
            const float* bhl = (l == 0) ? bhh0 : (bhh + (size_t)(l - 1) * 1536);
            for (int r = 0; r <= RMAX; r++) {
                const int NR = (r > 0) ? NRfull : 0;
                const int NG = (r < RMAX) ? NGfull : 0;
                round_k<<<NR + NG, 256, 0, stream>>>(
                    bin, K, Wl, bil, len, perm, nchp, gidx, g0, Bg, CHv, chsh,
                    xwbuf[r & 1], xwbuf[(r & 1) ^ 1],
                    whl, bhl, bout, hst, NR, r);
            }
            float* tmp = bin; bin = bout; bout = tmp;
        }
        pool_k<<<Bg, 256, 0, stream>>>(bin, len, perm, Wc, bc, out, g0);
    }
}

// Round 10
// 95217.871 us; speedup vs baseline: 1.0429x; 1.0429x over previous
//
#include <hip/hip_runtime.h>
#include <math.h>

// B=256 T=512 DIN=25 P=128 HID=256 3H=768 L=5 Q=0.15 EPS=1e-5
// Full-fp32. Base = R8's proven fused round_k (49.2ms, VGPR 52, 0 conflicts),
// with two surgical changes: (1) recur blocks process TWO adjacent-rank
// samples per 768KB Whh stream (same kq-split/gs-exchange code shape, acc
// doubled 12->24 regs); (2) single batch group Bg=256 (ws>=659MB proven in
// R2; CH=32 tier needs 646MB guaranteed, CH=64/747MB preferred). Critical
// path: 5 layers x 512 steps = 2560 sequential steps x ~6-7us port-bound.

// ---------------- stable sort + per-group chunk count ----------------
__global__ __launch_bounds__(256)
void sort_k(const int* __restrict__ len, int* __restrict__ perm,
            int* __restrict__ nchp, int Bg, int CHv)
{
    __shared__ int ll[256];
    __shared__ int lp[256];
    const int i = threadIdx.x;
    const int li = len[i];
    ll[i] = li;
    __syncthreads();
    int rk = 0;
    for (int j = 0; j < 256; j++) {
        int lj = ll[j];
        rk += (lj < li || (lj == li && j < i)) ? 1 : 0;
    }
    lp[rk] = i;
    __syncthreads();
    perm[i] = lp[i];
    const int ngrp = 256 / Bg;
    const int rmax = 512 / CHv;
    if (i < ngrp) {
        int mx = ll[lp[i * Bg + Bg - 1]];      // ascending -> last rank is max
        int nch = (mx + CHv - 1) / CHv;
        nchp[i] = nch < 1 ? 1 : (nch > rmax ? rmax : nch);
    }
}

// ---------------- Whh transpose: whhT[l][d][k][c] ----------------
__global__ __launch_bounds__(256)
void prep_whhT_k(const float* __restrict__ Whh0, const float* __restrict__ Whh,
                 float* __restrict__ out)
{
    int id = blockIdx.x * 256 + threadIdx.x;   // exactly 1,966,080 threads
    int u = id / 196608, rr = id % 196608;     // u = l*2+d
    int k = rr / 768, c = rr % 768;
    int l = u >> 1, d = u & 1;
    out[id] = (l == 0) ? Whh0[(size_t)(d * 768 + c) * 256 + k]
                       : Whh[(size_t)(((l - 1) * 2 + d) * 768 + c) * 256 + k];
}

// ---------------- input projection: LN -> FC(25->128) -> GELU -> FC(128->128) --
__global__ __launch_bounds__(128)
void input_proj_k(const float* __restrict__ x, const int* __restrict__ lengths,
                  const int* __restrict__ perm,
                  const float* __restrict__ lng, const float* __restrict__ lnb,
                  const float* __restrict__ w1, const float* __restrict__ b1v,
                  const float* __restrict__ w2, const float* __restrict__ b2v,
                  float* __restrict__ out, int g0)
{
    const int btl = blockIdx.x;
    const int sl  = btl >> 9;
    const int t   = btl & 511;
    const int b   = perm[g0 + sl];
    if (t >= lengths[b]) return;               // masked rows never read downstream
    const int tid = threadIdx.x;
    __shared__ float xs[25];
    __shared__ float xn[25];
    __shared__ float hs[128];
    if (tid < 25) xs[tid] = x[((size_t)b * 512 + t) * 25 + tid];
    __syncthreads();
    if (tid < 25) {
        float mu = 0.f;
        #pragma unroll
        for (int k = 0; k < 25; k++) mu += xs[k];
        mu *= (1.f / 25.f);
        float var = 0.f;
        #pragma unroll
        for (int k = 0; k < 25; k++) { float dd = xs[k] - mu; var += dd * dd; }
        var *= (1.f / 25.f);
        float rstd = 1.f / sqrtf(var + 1e-5f);
        xn[tid] = (xs[tid] - mu) * rstd * lng[tid] + lnb[tid];
    }
    __syncthreads();
    float a = b1v[tid];
    #pragma unroll
    for (int k = 0; k < 25; k++) a = fmaf(xn[k], w1[k * 128 + tid], a);
    float ge = 0.5f * a * (1.f + erff(a * 0.70710678118654752440f));
    hs[tid] = ge;
    __syncthreads();
    float o = b2v[tid];
    #pragma unroll 8
    for (int k = 0; k < 128; k++) o = fmaf(hs[k], w2[k * 128 + tid], o);
    out[(size_t)btl * 128 + tid] = o;
}

// ---------------- fused round: recur(chunk r-1) blocks FIRST, gemm(chunk r) --
// recur: NR = Bg blocks (2 dirs x Bg/2 pairs). TWO samples per block, 256 thr,
//   K split in quarters (kq) with float4 weight loads, gs partial exchange,
//   2 syncs/step — R8's exact shape with per-sample acc doubled.
// gemm: R8's 64Mx128N tile, 4x8/thread; 64 rows = (64/CHv) samples x CHv pos.
__global__ __launch_bounds__(256)
void round_k(const float* __restrict__ A, int K,
             const float* __restrict__ W,      // raw Wih layer slice [2][768][K]
             const float* __restrict__ bi,     // [2][768]
             const int* __restrict__ lengths, const int* __restrict__ perm,
             const int* __restrict__ nchp, int gidx, int g0, int Bg,
             int CHv, int chsh,
             float* __restrict__ xw_w,         // gemm out (round r)
             const float* __restrict__ xw_r,   // recur in (round r-1)
             const float* __restrict__ whhT,   // layer slice [2][256][768]
             const float* __restrict__ bhh,    // [2][768]
             float* __restrict__ Y,            // bout [Bg*512][512]
             float* __restrict__ hstate,       // [2*Bg][256]
             int NR, int r)
{
    __shared__ float As[8][68];        // gemm: [k][m]
    __shared__ float Bs[8][132];       // gemm: [k][n]
    __shared__ float h_s[2][260];      // recur: h state, sample-major scalar
    __shared__ float gs[2][4][776];    // recur: K-split partials per sample

    const int tid = threadIdx.x;
    const int nch = nchp[gidx];

    if ((int)blockIdx.x < NR) {
        // ================= recur role (2 samples, one dir) =================
        const int half = NR >> 1;
        const int d    = ((int)blockIdx.x >= half) ? 1 : 0;
        const int pr   = (int)blockIdx.x - d * half;
        const int b0   = pr * 2;
        const int lo   = d ? (nch - r) * CHv : (r - 1) * CHv;
        if (lo < 0 || lo >= 512) return;
        const int first = (r == 1);

        int nst[2];
        #pragma unroll
        for (int s = 0; s < 2; s++) {
            int L = lengths[perm[g0 + b0 + s]];
            int n = min(lo + CHv, L) - lo;
            nst[s] = (n < 0) ? 0 : n;
        }
        const int nmax = max(nst[0], nst[1]);
        if (!first && nmax <= 0) return;       // hstate already valid

        float* hg = hstate + (size_t)(d * Bg + b0) * 256;
        h_s[0][tid] = first ? 0.f : hg[tid];
        h_s[1][tid] = first ? 0.f : hg[256 + tid];
        __syncthreads();

        const int kq  = tid >> 6;              // K quarter 0..3
        const int q4  = (tid & 63) * 4;        // col-4 base within gate
        const float* Wd  = whhT + (size_t)d * 196608;
        const float* xwd = xw_r + (size_t)(d * Bg + b0) * ((size_t)CHv * 768);
        const float bh0 = bhh[d * 768 + tid];
        const float bh1 = bhh[d * 768 + 256 + tid];
        const float bh2 = bhh[d * 768 + 512 + tid];

        for (int st = 0; st < nmax; st++) {
            // phase 1: partial gh over this thread's K quarter, 12 cols x 2 samp
            float a0[2][4] = {}, a1[2][4] = {}, a2[2][4] = {};
            const float* wk = Wd + (size_t)(kq * 64) * 768 + q4;
            #pragma unroll 4
            for (int k4 = 0; k4 < 16; k4++) {
                const int kb = kq * 64 + k4 * 4;
                float ha[4], hb[4];
                #pragma unroll
                for (int kk = 0; kk < 4; kk++) {
                    ha[kk] = h_s[0][kb + kk];  // wave-uniform -> broadcast
                    hb[kk] = h_s[1][kb + kk];
                }
                const float* w0 = wk + (size_t)(k4 * 4) * 768;
                #pragma unroll
                for (int kk = 0; kk < 4; kk++) {
                    const float* wr = w0 + (size_t)kk * 768;
                    float4 wv0 = *(const float4*)(wr);
                    float4 wv1 = *(const float4*)(wr + 256);
                    float4 wv2 = *(const float4*)(wr + 512);
                    float u = ha[kk], v = hb[kk];
                    a0[0][0] = fmaf(u, wv0.x, a0[0][0]); a0[0][1] = fmaf(u, wv0.y, a0[0][1]);
                    a0[0][2] = fmaf(u, wv0.z, a0[0][2]); a0[0][3] = fmaf(u, wv0.w, a0[0][3]);
                    a1[0][0] = fmaf(u, wv1.x, a1[0][0]); a1[0][1] = fmaf(u, wv1.y, a1[0][1]);
                    a1[0][2] = fmaf(u, wv1.z, a1[0][2]); a1[0][3] = fmaf(u, wv1.w, a1[0][3]);
                    a2[0][0] = fmaf(u, wv2.x, a2[0][0]); a2[0][1] = fmaf(u, wv2.y, a2[0][1]);
                    a2[0][2] = fmaf(u, wv2.z, a2[0][2]); a2[0][3] = fmaf(u, wv2.w, a2[0][3]);
                    a0[1][0] = fmaf(v, wv0.x, a0[1][0]); a0[1][1] = fmaf(v, wv0.y, a0[1][1]);
                    a0[1][2] = fmaf(v, wv0.z, a0[1][2]); a0[1][3] = fmaf(v, wv0.w, a0[1][3]);
                    a1[1][0] = fmaf(v, wv1.x, a1[1][0]); a1[1][1] = fmaf(v, wv1.y, a1[1][1]);
                    a1[1][2] = fmaf(v, wv1.z, a1[1][2]); a1[1][3] = fmaf(v, wv1.w, a1[1][3]);
                    a2[1][0] = fmaf(v, wv2.x, a2[1][0]); a2[1][1] = fmaf(v, wv2.y, a2[1][1]);
                    a2[1][2] = fmaf(v, wv2.z, a2[1][2]); a2[1][3] = fmaf(v, wv2.w, a2[1][3]);
                }
            }
            #pragma unroll
            for (int s = 0; s < 2; s++) {
                *(float4*)&gs[s][kq][q4]       = make_float4(a0[s][0], a0[s][1], a0[s][2], a0[s][3]);
                *(float4*)&gs[s][kq][256 + q4] = make_float4(a1[s][0], a1[s][1], a1[s][2], a1[s][3]);
                *(float4*)&gs[s][kq][512 + q4] = make_float4(a2[s][0], a2[s][1], a2[s][2], a2[s][3]);
            }
            __syncthreads();
            // phase 2: gate update for hidden j = tid, both samples
            #pragma unroll
            for (int s = 0; s < 2; s++) {
                if (st < nst[s]) {
                    const int p = d ? (lo + nst[s] - 1 - st) : (lo + st);
                    float gr = bh0 + gs[s][0][tid] + gs[s][1][tid]
                                   + gs[s][2][tid] + gs[s][3][tid];
                    float gz = bh1 + gs[s][0][256 + tid] + gs[s][1][256 + tid]
                                   + gs[s][2][256 + tid] + gs[s][3][256 + tid];
                    float gn = bh2 + gs[s][0][512 + tid] + gs[s][1][512 + tid]
                                   + gs[s][2][512 + tid] + gs[s][3][512 + tid];
                    const float* xr = xwd + ((size_t)s * CHv + (p - lo)) * 768;
                    float rg = 1.f / (1.f + expf(-(xr[tid] + gr)));
                    float zg = 1.f / (1.f + expf(-(xr[256 + tid] + gz)));
                    float ng = tanhf(xr[512 + tid] + rg * gn);
                    float hv = h_s[s][tid];
                    float hn = (1.f - zg) * ng + zg * hv;
                    h_s[s][tid] = hn;
                    Y[((size_t)((b0 + s) * 512 + p)) * 512 + d * 256 + tid] = hn;
                }
            }
            __syncthreads();
        }
        hg[tid]       = h_s[0][tid];
        hg[256 + tid] = h_s[1][tid];
    } else {
        // ================= GEMM role (R8 verbatim, CHv-parametrized) =========
        const int gid  = blockIdx.x - NR;
        const int nt   = gid % 6;
        const int rest = gid / 6;
        const int spt  = 64 >> chsh;                   // samples per 64-row tile
        const int tpd  = Bg / spt;                     // tiles per dir
        const int dd   = (rest >= tpd) ? 1 : 0;
        const int rt   = rest - dd * tpd;
        const int s0   = rt * spt;
        const int lo   = dd ? (nch - 1 - r) * CHv : r * CHv;
        if (lo < 0 || lo >= 512) return;
        if (lengths[perm[g0 + s0 + spt - 1]] <= lo) return;  // ascending sort

        float acc[4][8] = {};
        const int tm = tid >> 4;                 // rows tm*4..+3
        const int tn = tid & 15;                 // cols {tn*4..+3, 64+tn*4..+3}
        const int arr = tid >> 2, ak = (tid & 3) * 2;
        const int bn = tid >> 1, bk = (tid & 1) * 4;

        const int sA = s0 + (arr >> chsh);
        const int pA = lo + (arr & (CHv - 1));
        const float* Ap = A + ((size_t)sA * 512 + pA) * K + ak;
        const float* Wp = W + ((size_t)dd * 768 + nt * 128 + bn) * K + bk;

        for (int k0 = 0; k0 < K; k0 += 8) {
            float2 av = *(const float2*)(Ap + k0);
            float4 bv = *(const float4*)(Wp + k0);
            __syncthreads();
            As[ak][arr] = av.x; As[ak + 1][arr] = av.y;
            Bs[bk + 0][bn] = bv.x; Bs[bk + 1][bn] = bv.y;
            Bs[bk + 2][bn] = bv.z; Bs[bk + 3][bn] = bv.w;
            __syncthreads();
            #pragma unroll
            for (int kk = 0; kk < 8; kk++) {
                float4 a4 = *(const float4*)&As[kk][tm * 4];
                float4 b0v = *(const float4*)&Bs[kk][tn * 4];
                float4 b1v = *(const float4*)&Bs[kk][64 + tn * 4];
                float ar4[4] = {a4.x, a4.y, a4.z, a4.w};
                float br[8] = {b0v.x, b0v.y, b0v.z, b0v.w,
                               b1v.x, b1v.y, b1v.z, b1v.w};
                #pragma unroll
                for (int i = 0; i < 4; i++)
                    #pragma unroll
                    for (int j = 0; j < 8; j++)
                        acc[i][j] = fmaf(ar4[i], br[j], acc[i][j]);
            }
        }
        const int cb = dd * 768 + nt * 128;
        float bv0[4], bv1[4];
        #pragma unroll
        for (int j = 0; j < 4; j++) {
            bv0[j] = bi[cb + tn * 4 + j];
            bv1[j] = bi[cb + 64 + tn * 4 + j];
        }
        #pragma unroll
        for (int i = 0; i < 4; i++) {
            const int row = tm * 4 + i;
            const int sl  = s0 + (row >> chsh);
            const int po  = row & (CHv - 1);
            float* o = xw_w + (size_t)((dd * Bg + sl) * CHv + po) * 768
                     + nt * 128 + tn * 4;
            float4 c0 = make_float4(acc[i][0] + bv0[0], acc[i][1] + bv0[1],
                                    acc[i][2] + bv0[2], acc[i][3] + bv0[3]);
            float4 c1 = make_float4(acc[i][4] + bv1[0], acc[i][5] + bv1[1],
                                    acc[i][6] + bv1[2], acc[i][7] + bv1[3]);
            *(float4*)(o)      = c0;
            *(float4*)(o + 64) = c1;
        }
    }
}

// ---------------- top-Q pooling + classifier head ----------------
__global__ __launch_bounds__(256)
void pool_k(const float* __restrict__ H, const int* __restrict__ lengths,
            const int* __restrict__ perm,
            const float* __restrict__ Wc, const float* __restrict__ bcp,
            float* __restrict__ out, int g0)
{
    const int bl = blockIdx.x;
    const int b  = perm[g0 + bl];
    const int tid = threadIdx.x;
    __shared__ float sc[512];
    __shared__ int   sel[128];
    __shared__ int   nsel;
    __shared__ float red[256];
    const int len = lengths[b];
    const int k = max(1, (int)ceilf((float)len * 0.15f));   // jnp fp32 semantics
    if (tid == 0) nsel = 0;
    for (int t = tid; t < 512; t += 256) {
        float s;
        if (t < len) {
            const float* row = H + ((size_t)bl * 512 + t) * 512;
            float acc = 0.f;
            for (int j = 0; j < 512; j++) acc = fmaf(row[j], row[j], acc);
            s = sqrtf(acc);
        } else s = -1e9f;
        sc[t] = s;
    }
    __syncthreads();
    // stable top-k: include t iff (#strictly greater) + (#equal, smaller idx) < k
    for (int t = tid; t < 512; t += 256) {
        if (t < len) {
            const float s = sc[t];
            int cnt = 0;
            for (int u = 0; u < 512; u++) {
                float su = sc[u];
                cnt += (su > s || (su == s && u < t)) ? 1 : 0;
            }
            if (cnt < k) { int p = atomicAdd(&nsel, 1); sel[p] = t; }
        }
    }
    __syncthreads();
    const int ns = nsel;                       // == k
    float part = 0.f;
    for (int j = tid; j < 512; j += 256) {
        float acc = 0.f;
        for (int i = 0; i < ns; i++)
            acc += H[((size_t)bl * 512 + sel[i]) * 512 + j];
        part += (acc / (float)k) * Wc[j];
    }
    red[tid] = part;
    __syncthreads();
    for (int s2 = 128; s2 > 0; s2 >>= 1) {
        if (tid < s2) red[tid] += red[tid + s2];
        __syncthreads();
    }
    if (tid == 0) out[b] = red[0] + bcp[0];
}

// ---------------- host ----------------
static inline size_t alup(size_t x) { return (x + 255) & ~255ull; }

static size_t tier_bytes(int Bg, int CHv)
{
    return 2 * alup((size_t)Bg * 512 * 512 * 4)            // H ping-pong
         + 2 * alup((size_t)Bg * 2 * CHv * 768 * 4)        // xw ping-pong
         + alup(1966080ull * 4)                            // whhT
         + alup((size_t)Bg * 2 * 256 * 4)                  // hstate
         + alup(2048);                                     // perm + nch
}

extern "C" void kernel_launch(void* const* d_in, const int* in_sizes, int n_in,
                              void* d_out, int out_size, void* d_ws, size_t ws_size,
                              hipStream_t stream)
{
    const float* x    = (const float*)d_in[0];
    const int*   len  = (const int*)  d_in[1];
    const float* ln_g = (const float*)d_in[2];
    const float* ln_b = (const float*)d_in[3];
    const float* w1   = (const float*)d_in[4];
    const float* b1   = (const float*)d_in[5];
    const float* w2   = (const float*)d_in[6];
    const float* b2   = (const float*)d_in[7];
    const float* Wih0 = (const float*)d_in[8];
    const float* Whh0 = (const float*)d_in[9];
    const float* bih0 = (const float*)d_in[10];
    const float* bhh0 = (const float*)d_in[11];
    const float* Wih  = (const float*)d_in[12];
    const float* Whh  = (const float*)d_in[13];
    const float* bih  = (const float*)d_in[14];
    const float* bhh  = (const float*)d_in[15];
    const float* Wc   = (const float*)d_in[16];
    const float* bc   = (const float*)d_in[17];
    float* out = (float*)d_out;

    // tier ladder: prefer one big group; (256,32) needs 646MB <= proven 659MB
    const int tBg[7] = {256, 256, 128, 128, 64, 32, 16};
    const int tCH[7] = { 64,  32,  64,  32, 64, 64, 64};
    int Bg = 0, CHv = 64;
    for (int i = 0; i < 7; i++)
        if (ws_size >= tier_bytes(tBg[i], tCH[i])) { Bg = tBg[i]; CHv = tCH[i]; break; }
    if (Bg == 0) return;
    const int chsh = (CHv == 64) ? 6 : 5;
    const int RMAX = 512 / CHv;

    char* ws = (char*)d_ws;
    size_t off = 0;
    auto alloc = [&](size_t bytes) { size_t o = off; off += alup(bytes); return o; };
    float* h0   = (float*)(ws + alloc((size_t)Bg * 512 * 512 * 4));
    float* h1   = (float*)(ws + alloc((size_t)Bg * 512 * 512 * 4));
    float* xwA  = (float*)(ws + alloc((size_t)Bg * 2 * CHv * 768 * 4));
    float* xwB  = (float*)(ws + alloc((size_t)Bg * 2 * CHv * 768 * 4));
    float* whhT = (float*)(ws + alloc(1966080ull * 4));
    float* hst  = (float*)(ws + alloc((size_t)Bg * 2 * 256 * 4));
    int*   perm = (int*)  (ws + alloc(2048));
    int*   nchp = perm + 256;
    float* xwbuf[2] = {xwA, xwB};

    sort_k<<<1, 256, 0, stream>>>(len, perm, nchp, Bg, CHv);
    prep_whhT_k<<<7680, 256, 0, stream>>>(Whh0, Whh, whhT);

    const int NRfull = Bg;                         // 2 dirs x Bg/2 sample pairs
    const int NGfull = 6 * 2 * Bg * CHv / 64;      // 6 col tiles x row tiles

    for (int g0 = 0; g0 < 256; g0 += Bg) {
        const int gidx = g0 / Bg;
        input_proj_k<<<Bg * 512, 128, 0, stream>>>(x, len, perm, ln_g, ln_b,
                                                   w1, b1, w2, b2, h0, g0);
        float* bin = h0;
        float* bout = h1;
        for (int l = 0; l < 5; l++) {
            const int K = (l == 0) ? 128 : 512;
            const float* Wl  = (l == 0) ? Wih0 : (Wih + (size_t)(l - 1) * 2 * 768 * 512);
            const float* bil = (l == 0) ? bih0 : (bih + (size_t)(l - 1) * 1536);
            const float* whl = whhT + (size_t)l * 393216;
            const float* bhl = (l == 0) ? bhh0 : (bhh + (size_t)(l - 1) * 1536);
            for (int r = 0; r <= RMAX; r++) {
                const int NR = (r > 0) ? NRfull : 0;
                const int NG = (r < RMAX) ? NGfull : 0;
                round_k<<<NR + NG, 256, 0, stream>>>(
                    bin, K, Wl, bil, len, perm, nchp, gidx, g0, Bg, CHv, chsh,
                    xwbuf[r & 1], xwbuf[(r & 1) ^ 1],
                    whl, bhl, bout, hst, NR, r);
            }
            float* tmp = bin; bin = bout; bout = tmp;
        }
        pool_k<<<Bg, 256, 0, stream>>>(bin, len, perm, Wc, bc, out, g0);
    }
}